// Round 1
// baseline (182.680 us; speedup 1.0000x reference)
//
#include <hip/hip_runtime.h>

// GraphConvolution: out = relu(D^-1/2 (2I - adj) D^-1/2 (input@weight) + b)
// N=8192, F_in=512, F_out=256. All inputs f32; internal GEMMs in fp16 MFMA
// (fp16 not bf16: the N=8192 cancellation-heavy sum needs 2^-12 rounding).

typedef _Float16 h4 __attribute__((ext_vector_type(4)));
typedef _Float16 h8 __attribute__((ext_vector_type(8)));
typedef float f4 __attribute__((ext_vector_type(4)));

__device__ __forceinline__ void gload_lds16(const void* g, void* l) {
    __builtin_amdgcn_global_load_lds(
        (const __attribute__((address_space(1))) void*)g,
        (__attribute__((address_space(3))) void*)l, 16, 0, 0);
}

// ---------------------------------------------------------------------------
// k0: weight [512][256] f32 -> W^T [256 j][512 k] fp16, XOR-swizzled within
// each 128B (64-elem) k-chunk: byte ^= ((j&7)<<4). Lets k2 global_load_lds it
// linearly while ds_reads apply the same XOR (bank-conflict-free b128 reads).
__global__ __launch_bounds__(256) void k0_wt(const float* __restrict__ weight,
                                             char* __restrict__ wt) {
    const int idx = blockIdx.x * 256 + threadIdx.x;   // 131072 total
    const int k = idx >> 8, j = idx & 255;
    const _Float16 h = (_Float16)weight[idx];
    const int off = j * 1024 + ((k >> 6) << 7) + (((k & 63) << 1) ^ ((j & 7) << 4));
    *(_Float16*)(wt + off) = h;
}

// ---------------------------------------------------------------------------
// k1: dinv[r] = 1/sqrt(2 + sum_k adj[r][k])
__global__ __launch_bounds__(256) void k1_deg(const float* __restrict__ adj,
                                              float* __restrict__ dinv) {
    const int r = blockIdx.x;
    const float4* rp = (const float4*)(adj + (size_t)r * 8192);
    const int t = threadIdx.x;
    float s = 0.f;
#pragma unroll
    for (int i = 0; i < 8; ++i) {
        float4 v = rp[t + i * 256];
        s += (v.x + v.y) + (v.z + v.w);
    }
#pragma unroll
    for (int off = 32; off > 0; off >>= 1) s += __shfl_down(s, off, 64);
    __shared__ float part[4];
    if ((t & 63) == 0) part[t >> 6] = s;
    __syncthreads();
    if (t == 0) {
        float deg = (part[0] + part[1]) + (part[2] + part[3]);
        dinv[r] = 1.0f / sqrtf(2.0f + deg);
    }
}

// ---------------------------------------------------------------------------
// k2: support = input @ weight; writes S'^T[j][k] = dinv[k]*support[k][j] as
// fp16, transposed + pre-swizzled (same 128B-chunk XOR as k0).
// Block: 64 rows x 256 cols, 8 waves, K=512 in 8 steps of BK=64.
__global__ __launch_bounds__(512) void k2_support(const float* __restrict__ input,
                                                  const char* __restrict__ wt,
                                                  const float* __restrict__ dinv,
                                                  char* __restrict__ sT) {
    __shared__ char smem[8192 + 32768];   // A [64][128B] + B [256][128B]
    const int t = threadIdx.x, w = t >> 6, l = t & 63;
    const int r0 = (int)blockIdx.x * 64;
    const int ar = t >> 4, ac4 = t & 15;
    const int bj = l >> 3, bb = (l & 7) * 16;

    f4 acc[4][2] = {};

    for (int kt = 0; kt < 8; ++kt) {
        const int k0 = kt * 64;
        __syncthreads();
        // stage A: input rows -> fp16, swizzled
#pragma unroll
        for (int hh = 0; hh < 2; ++hh) {
            const int row = ar + hh * 32;
            float4 v = *(const float4*)(input + (size_t)(r0 + row) * 512 + k0 + ac4 * 4);
            h4 h;
            h[0] = (_Float16)v.x; h[1] = (_Float16)v.y;
            h[2] = (_Float16)v.z; h[3] = (_Float16)v.w;
            *(h4*)(smem + row * 128 + ((ac4 * 8) ^ ((row & 7) << 4))) = h;
        }
        // stage B: W^T tile [256][64] fp16 via global_load_lds (pre-swizzled src)
#pragma unroll
        for (int q = 0; q < 4; ++q) {
            const int c = w * 4 + q;
            gload_lds16(wt + (size_t)(c * 8 + bj) * 1024 + kt * 128 + bb,
                        smem + 8192 + c * 1024);
        }
        __syncthreads();
#pragma unroll
        for (int kk = 0; kk < 2; ++kk) {
            const int kb = (kk * 32 + ((l >> 4) << 3)) << 1;
            h8 b[2];
#pragma unroll
            for (int n = 0; n < 2; ++n) {
                const int j = w * 32 + n * 16 + (l & 15);
                b[n] = *(const h8*)(smem + 8192 + j * 128 + (kb ^ ((j & 7) << 4)));
            }
#pragma unroll
            for (int m = 0; m < 4; ++m) {
                const int r = m * 16 + (l & 15);
                h8 a = *(const h8*)(smem + r * 128 + (kb ^ ((r & 7) << 4)));
                acc[m][0] = __builtin_amdgcn_mfma_f32_16x16x32_f16(a, b[0], acc[m][0], 0, 0, 0);
                acc[m][1] = __builtin_amdgcn_mfma_f32_16x16x32_f16(a, b[1], acc[m][1], 0, 0, 0);
            }
        }
    }
    // epilogue: S'^T[j][k] fp16, pre-swizzled. C/D: col=l&15, row=(l>>4)*4+reg.
#pragma unroll
    for (int m = 0; m < 4; ++m)
#pragma unroll
        for (int n = 0; n < 2; ++n) {
            const int j = w * 32 + n * 16 + (l & 15);
            const int k0r = r0 + m * 16 + ((l >> 4) << 2);
            h4 h;
#pragma unroll
            for (int r = 0; r < 4; ++r)
                h[r] = (_Float16)(dinv[k0r + r] * acc[m][n][r]);
            const int off = j * 16384 + (((k0r & 8191) >> 6) << 7) +
                            (((k0r & 63) << 1) ^ ((j & 7) << 4));
            *(h4*)(sT + off) = h;
        }
}

// ---------------------------------------------------------------------------
// k3: out[i][j] = relu(dinv[i] * sum_k (2*I - adj)[i][k] * S'T[j][k] + b[j])
// BM=32, BN=256, BK=64, 8 waves, 256 blocks (1/CU). Double-buffered LDS.
// A reg-staged (f32 load -> diag transform -> fp16 -> swizzled ds_write);
// B via global_load_lds from pre-swizzled S'^T.
__global__ __launch_bounds__(512, 2) void k3_spmm(const float* __restrict__ adj,
                                                  const char* __restrict__ sT,
                                                  const float* __restrict__ dinv,
                                                  const float* __restrict__ bias,
                                                  float* __restrict__ out) {
    __shared__ char smem[2 * 36864];   // per buf: A [32][128B]=4KB, B [256][128B]=32KB
    const int t = threadIdx.x;
    const int w = t >> 6, l = t & 63;
    const int i0 = (int)blockIdx.x * 32;

    const int arow = t >> 4;            // 0..31 (16 threads per row)
    const int ac4 = t & 15;             // float4 index along k
    const int arow_g = i0 + arow;
    const float* aptr = adj + (size_t)arow_g * 8192 + ac4 * 4;
    const int a_off = arow * 128 + ((ac4 * 8) ^ ((arow & 7) << 4));

    const int bj = l >> 3, bb = (l & 7) * 16;

    f4 acc[2][2] = {};

    auto stageB = [&](int kt, int buf) {
        char* bl = smem + buf * 36864 + 4096;
#pragma unroll
        for (int q = 0; q < 4; ++q) {
            const int c = w * 4 + q;
            gload_lds16(sT + (size_t)(c * 8 + bj) * 16384 + kt * 128 + bb,
                        bl + c * 1024);
        }
    };
    auto writeA = [&](int kt, const float4 v, int buf) {
        const int kg = kt * 64 + ac4 * 4;
        h4 h;  // A~ = 2I - adj, folded here so no separate support term needed
        h[0] = (_Float16)((arow_g == kg    ) ? 2.0f - v.x : -v.x);
        h[1] = (_Float16)((arow_g == kg + 1) ? 2.0f - v.y : -v.y);
        h[2] = (_Float16)((arow_g == kg + 2) ? 2.0f - v.z : -v.z);
        h[3] = (_Float16)((arow_g == kg + 3) ? 2.0f - v.w : -v.w);
        *(h4*)(smem + buf * 36864 + a_off) = h;
    };
    auto compute = [&](int buf) {
        const char* A = smem + buf * 36864;
        const char* B = smem + buf * 36864 + 4096;
#pragma unroll
        for (int kk = 0; kk < 2; ++kk) {
            const int kb = (kk * 32 + ((l >> 4) << 3)) << 1;
            h8 a[2], b[2];
#pragma unroll
            for (int m = 0; m < 2; ++m) {
                const int r = m * 16 + (l & 15);
                a[m] = *(const h8*)(A + r * 128 + (kb ^ ((r & 7) << 4)));
            }
#pragma unroll
            for (int n = 0; n < 2; ++n) {
                const int j = w * 32 + n * 16 + (l & 15);
                b[n] = *(const h8*)(B + j * 128 + (kb ^ ((j & 7) << 4)));
            }
#pragma unroll
            for (int m = 0; m < 2; ++m)
#pragma unroll
                for (int n = 0; n < 2; ++n)
                    acc[m][n] = __builtin_amdgcn_mfma_f32_16x16x32_f16(a[m], b[n], acc[m][n], 0, 0, 0);
        }
    };

    // prologue
    float4 a0 = *(const float4*)aptr;
    stageB(0, 0);
    writeA(0, a0, 0);
    __syncthreads();

    int cur = 0;
    for (int kt = 0; kt < 128; ++kt) {
        const bool pf = (kt + 1) < 128;
        float4 an;
        if (pf) {
            an = *(const float4*)(aptr + (size_t)(kt + 1) * 64);
            stageB(kt + 1, cur ^ 1);
        }
        compute(cur);
        if (pf) writeA(kt + 1, an, cur ^ 1);
        __syncthreads();
        cur ^= 1;
    }

    // epilogue: out = relu(dinv[i]*acc + b[j]) straight to d_out
#pragma unroll
    for (int m = 0; m < 2; ++m)
#pragma unroll
        for (int n = 0; n < 2; ++n) {
            const int j = w * 32 + n * 16 + (l & 15);
            const float bjv = bias[j];
            const int ib = i0 + m * 16 + ((l >> 4) << 2);
            float* op = out + (size_t)ib * 256 + j;
#pragma unroll
            for (int r = 0; r < 4; ++r) {
                float v = dinv[ib + r] * acc[m][n][r] + bjv;
                op[(size_t)r * 256] = v > 0.f ? v : 0.f;
            }
        }
}

// ---------------------------------------------------------------------------
extern "C" void kernel_launch(void* const* d_in, const int* in_sizes, int n_in,
                              void* d_out, int out_size, void* d_ws, size_t ws_size,
                              hipStream_t stream) {
    const float* input  = (const float*)d_in[0];   // [8192][512]
    const float* adj    = (const float*)d_in[1];   // [8192][8192]
    const float* weight = (const float*)d_in[2];   // [512][256]
    const float* bias   = (const float*)d_in[3];   // [256]
    float* out = (float*)d_out;                    // [8192][256]

    char* ws = (char*)d_ws;
    float* dinv = (float*)ws;                 // 32 KB
    char*  wt   = ws + 32768;                 // 256 KB  (W^T fp16, swizzled)
    char*  sT   = ws + 294912;                // 4 MB    (S'^T fp16, swizzled)

    k0_wt<<<512, 256, 0, stream>>>(weight, wt);
    k1_deg<<<8192, 256, 0, stream>>>(adj, dinv);
    k2_support<<<128, 512, 0, stream>>>(input, wt, dinv, sT);
    k3_spmm<<<256, 512, 0, stream>>>(adj, sT, dinv, bias, out);
}